// Round 1
// 726.683 us; speedup vs baseline: 1.0863x; 1.0863x over previous
//
#include <hip/hip_runtime.h>
#include <hip/hip_bf16.h>
#include <cstdint>

// ---------------------------------------------------------------------------
// CrossModalAttention, R3: pipelined K-loop (double-buffered LDS + counted
// vmcnt, raw s_barrier -- never drain vmcnt to 0 in the main loop) + merged
// q/resid gemm over stacked [Wqc; Wc].
// Pipeline:
//   Wqc = Wq*Wc -> Wstack[0:512], Wc -> Wstack[512:1024]; Wkve = [Wk;Wv]*We
//   [q_t; resid] = Wstack@Xc,  [k_t;v_nt] = Wkve@Xe
//   P = exp(QK^T) bf16 + atomic rowsums;  out = gamma*(V@P^T)/rowsum + resid
// All gemms: 128x128 tile, BK=32, mfma_f32_16x16x32_bf16, global_load_lds(16B),
// XOR-swizzled LDS (0 bank conflicts, R1-verified), 2-deep LDS dbuf w/ vmcnt(4).
// ---------------------------------------------------------------------------

typedef __hip_bfloat16 bf16;
typedef __bf16 bf16x8 __attribute__((ext_vector_type(8)));
typedef float f32x4 __attribute__((ext_vector_type(4)));

#define NB   32
#define NTOK 1024
#define NHID 512
#define CEFF 1280
#define WSZ  (NHID*NHID)          // 262144 = 1<<18

// ---------------------------------------------------------------------------
// 4 square fp32 weights -> contiguous bf16 [Wc, Wq, Wk, Wv]
struct W4 { const float* s[4]; };
__global__ __launch_bounds__(256) void convert_w4_kernel(W4 w, bf16* __restrict__ dst) {
    int i = blockIdx.x * 256 + threadIdx.x;
    int sel = i >> 18, off = i & (WSZ - 1);
    dst[i] = __float2bfloat16(w.s[sel][off]);
}

// fp32 [B][C][N] -> bf16 [B][N][C] (transpose + convert), 32x32 LDS tile
__global__ __launch_bounds__(256) void transpose_to_bf16_kernel(const float* __restrict__ in,
                                                                bf16* __restrict__ out,
                                                                int C, int N) {
    __shared__ float tile[32][33];
    const int n0 = blockIdx.x * 32, c0 = blockIdx.y * 32, b = blockIdx.z;
    in  += (size_t)b * C * N;
    out += (size_t)b * N * C;
    const int tx = threadIdx.x, ty = threadIdx.y;
    #pragma unroll
    for (int i = ty; i < 32; i += 8)
        tile[i][tx] = in[(size_t)(c0 + i) * N + n0 + tx];
    __syncthreads();
    #pragma unroll
    for (int i = ty; i < 32; i += 8)
        out[(size_t)(n0 + i) * C + c0 + tx] = __float2bfloat16(tile[tx][i]);
}

// fused biases: bqc = bq + Wq*bc ; bkv = [bk + Wk*be ; bv + Wv*be]
__global__ __launch_bounds__(256) void bias_fuse_kernel(
    const float* __restrict__ Wq, const float* __restrict__ Wk, const float* __restrict__ Wv,
    const float* __restrict__ bc, const float* __restrict__ be,
    const float* __restrict__ bq, const float* __restrict__ bk, const float* __restrict__ bv,
    float* __restrict__ bqc, float* __restrict__ bkv) {
    const int r = blockIdx.x, t = threadIdx.x;
    const float* Wrow; const float* vin; float badd; float* dst;
    if (r < 512)       { Wrow = Wq + (size_t)r * 512;          vin = bc; badd = bq[r];        dst = bqc + r; }
    else if (r < 1024) { Wrow = Wk + (size_t)(r - 512) * 512;  vin = be; badd = bk[r - 512];  dst = bkv + (r - 512); }
    else               { Wrow = Wv + (size_t)(r - 1024) * 512; vin = be; badd = bv[r - 1024]; dst = bkv + (r - 512); }
    float s = Wrow[t] * vin[t] + Wrow[t + 256] * vin[t + 256];
    #pragma unroll
    for (int off = 32; off >= 1; off >>= 1) s += __shfl_xor(s, off, 64);
    __shared__ float red[4];
    if ((t & 63) == 0) red[t >> 6] = s;
    __syncthreads();
    if (t == 0) dst[0] = red[0] + red[1] + red[2] + red[3] + badd;
}

// ---------------------------------------------------------------------------
// gemm_bt: C[bz][m][n] = sum_k A[bz][m][k] * B[bz][n][k]  (+ bias[m])
// swiz=1: grid (8, nx*ny -> (x=by&7,y=by>>3), z) so batch -> fixed XCD.
// K-loop: 2-deep LDS double buffer; stage(t+1) issued BEFORE compute(t);
// s_waitcnt vmcnt(4) (counted, never 0 mid-loop) + raw s_barrier.
// Epilogues:
//   doExp: v = exp(v) before bf16 stores / rowsum
//   rsumOut: atomic per-(bz,m)-row sums of v  (QK)
//   outF (fp32 [m][n]): gamma * v / rsumIn[bz][n] + residH (bf16 [m][n])
//   outHt (bf16 [n][m], rows m<htMax), outHn (bf16 [m-hnBase][n], rows m>=hnBase)
__global__ __launch_bounds__(256) void gemm_bt_kernel(
    const bf16* __restrict__ A, long long aStride, int lda,
    const bf16* __restrict__ Bt, long long bStride, int ldb,
    int K, int swiz,
    const float* __restrict__ bias,
    float* __restrict__ outF, long long fStride, int ldf,
    const bf16* __restrict__ residH, const float* __restrict__ gammaPtr,
    const float* __restrict__ rsumIn,
    float* __restrict__ rsumOut,
    bf16* __restrict__ outHt, long long htStride, int ldht, int htMax,
    bf16* __restrict__ outHn, long long hnStride, int ldhn, int hnBase, int doExp)
{
    __shared__ __bf16 lA[2][128 * 32];
    __shared__ __bf16 lB[2][128 * 32];
    __shared__ float lrs[128];

    const int tid  = threadIdx.x;
    const int wave = tid >> 6;
    const int lane = tid & 63;

    int bx, by, bz;
    if (swiz) { bx = (int)blockIdx.y & 7; by = (int)blockIdx.y >> 3; bz = (int)blockIdx.z * 8 + (int)blockIdx.x; }
    else      { bx = (int)blockIdx.x;     by = (int)blockIdx.y;      bz = (int)blockIdx.z; }
    const int m0 = by * 128;
    const int n0 = bx * 128;

    const bf16* Ab = A  + (size_t)bz * aStride;
    const bf16* Bb = Bt + (size_t)bz * bStride;

    const int wm = wave >> 1, wn = wave & 1;
    const int lrow = lane & 15, quad = lane >> 4;

    f32x4 acc[4][4];
    #pragma unroll
    for (int i = 0; i < 4; i++)
        #pragma unroll
        for (int j = 0; j < 4; j++)
            acc[i][j] = (f32x4){0.f, 0.f, 0.f, 0.f};

    // staging (XOR-swizzled chunk layout; R1-verified 0 conflicts)
    const int rowl = lane >> 2;
    const int qsw  = (lane & 3) ^ ((lane >> 3) & 3);
    const bf16* gA0 = Ab + (size_t)(m0 +      wave * 16 + rowl) * lda + qsw * 8;
    const bf16* gA1 = Ab + (size_t)(m0 + 64 + wave * 16 + rowl) * lda + qsw * 8;
    const bf16* gB0 = Bb + (size_t)(n0 +      wave * 16 + rowl) * ldb + qsw * 8;
    const bf16* gB1 = Bb + (size_t)(n0 + 64 + wave * 16 + rowl) * ldb + qsw * 8;
    const int dst0 = (wave * 64) * 8;
    const int dst1 = (256 + wave * 64) * 8;

    const int sw = quad ^ ((lrow >> 1) & 3);
    int aoff[4], boff[4];
    #pragma unroll
    for (int mt = 0; mt < 4; mt++) aoff[mt] = ((wm * 4 + mt) * 64 + lrow * 4 + sw) * 8;
    #pragma unroll
    for (int nt = 0; nt < 4; nt++) boff[nt] = ((wn * 4 + nt) * 64 + lrow * 4 + sw) * 8;

    auto stage = [&](int k0, int b) {
        __builtin_amdgcn_global_load_lds((const __attribute__((address_space(1))) void*)(gA0 + k0),
                                         (__attribute__((address_space(3))) void*)(&lA[b][dst0]), 16, 0, 0);
        __builtin_amdgcn_global_load_lds((const __attribute__((address_space(1))) void*)(gA1 + k0),
                                         (__attribute__((address_space(3))) void*)(&lA[b][dst1]), 16, 0, 0);
        __builtin_amdgcn_global_load_lds((const __attribute__((address_space(1))) void*)(gB0 + k0),
                                         (__attribute__((address_space(3))) void*)(&lB[b][dst0]), 16, 0, 0);
        __builtin_amdgcn_global_load_lds((const __attribute__((address_space(1))) void*)(gB1 + k0),
                                         (__attribute__((address_space(3))) void*)(&lB[b][dst1]), 16, 0, 0);
    };

    auto compute = [&](int b) {
        const __bf16* __restrict__ pA = lA[b];
        const __bf16* __restrict__ pB = lB[b];
        bf16x8 af[4], bfr[4];
        #pragma unroll
        for (int mt = 0; mt < 4; mt++) af[mt]  = *(const bf16x8*)&pA[aoff[mt]];
        #pragma unroll
        for (int nt = 0; nt < 4; nt++) bfr[nt] = *(const bf16x8*)&pB[boff[nt]];
        #pragma unroll
        for (int mt = 0; mt < 4; mt++)
            #pragma unroll
            for (int nt = 0; nt < 4; nt++)
                acc[mt][nt] = __builtin_amdgcn_mfma_f32_16x16x32_bf16(af[mt], bfr[nt], acc[mt][nt], 0, 0, 0);
    };

    // prologue: tile 0 -> buf 0
    stage(0, 0);
    int cur = 0;
    for (int k0 = 32; k0 < K; k0 += 32) {
        stage(k0, cur ^ 1);                                   // next tile in flight
        asm volatile("s_waitcnt vmcnt(4)" ::: "memory");      // only tile-t's 4 loads
        __builtin_amdgcn_s_barrier();
        asm volatile("" ::: "memory");
        compute(cur);
        asm volatile("s_waitcnt lgkmcnt(0)" ::: "memory");    // ds_reads done before restage
        __builtin_amdgcn_s_barrier();
        cur ^= 1;
    }
    asm volatile("s_waitcnt vmcnt(0)" ::: "memory");
    __builtin_amdgcn_s_barrier();
    asm volatile("" ::: "memory");
    compute(cur);

    // ---- epilogue (D frag: col=lane&15, row=quad*4+reg) ----
    const float gscale = gammaPtr ? gammaPtr[0] : 1.0f;
    float rs[4][4];
    if (rsumOut)
        #pragma unroll
        for (int mt = 0; mt < 4; mt++)
            #pragma unroll
            for (int r = 0; r < 4; r++) rs[mt][r] = 0.f;

    #pragma unroll
    for (int mt = 0; mt < 4; mt++) {
        const int mbase = m0 + wm * 64 + mt * 16 + quad * 4;
        float bv[4];
        #pragma unroll
        for (int r = 0; r < 4; r++) bv[r] = bias ? bias[mbase + r] : 0.f;
        #pragma unroll
        for (int nt = 0; nt < 4; nt++) {
            const int n = n0 + wn * 64 + nt * 16 + lrow;
            float v[4];
            #pragma unroll
            for (int r = 0; r < 4; r++) {
                v[r] = acc[mt][nt][r] + bv[r];
                if (doExp) v[r] = __expf(v[r]);
                if (rsumOut) rs[mt][r] += v[r];
            }
            if (outF) {
                float* p = outF + (size_t)bz * fStride;
                const bf16* rp = residH + (size_t)bz * fStride;
                const float rinv = rsumIn ? 1.0f / rsumIn[(size_t)bz * NTOK + n] : 1.0f;
                #pragma unroll
                for (int r = 0; r < 4; r++) {
                    size_t idx = (size_t)(mbase + r) * ldf + n;
                    p[idx] = gscale * v[r] * rinv + __bfloat162float(rp[idx]);
                }
            }
            if (outHt && mbase < htMax) {
                union { bf16 h[4]; unsigned long long u; } pk;
                #pragma unroll
                for (int r = 0; r < 4; r++) pk.h[r] = __float2bfloat16(v[r]);
                *(unsigned long long*)&outHt[(size_t)bz * htStride + (size_t)n * ldht + mbase] = pk.u;
            }
            if (outHn && mbase >= hnBase) {
                bf16* p = outHn + (size_t)bz * hnStride;
                #pragma unroll
                for (int r = 0; r < 4; r++)
                    p[(size_t)(mbase - hnBase + r) * ldhn + n] = __float2bfloat16(v[r]);
            }
        }
    }

    if (rsumOut) {
        #pragma unroll
        for (int mt = 0; mt < 4; mt++)
            #pragma unroll
            for (int r = 0; r < 4; r++) {
                float s = rs[mt][r];
                s += __shfl_xor(s, 1, 64);
                s += __shfl_xor(s, 2, 64);
                s += __shfl_xor(s, 4, 64);
                s += __shfl_xor(s, 8, 64);
                rs[mt][r] = s;
            }
        if (tid < 128) lrs[tid] = 0.f;
        __syncthreads();
        if (lrow == 0) {
            #pragma unroll
            for (int mt = 0; mt < 4; mt++)
                #pragma unroll
                for (int r = 0; r < 4; r++)
                    atomicAdd(&lrs[wm * 64 + mt * 16 + quad * 4 + r], rs[mt][r]);
        }
        __syncthreads();
        if (tid < 128) atomicAdd(&rsumOut[(size_t)bz * NTOK + m0 + tid], lrs[tid]);
    }
}

// ---------------------------------------------------------------------------
extern "C" void kernel_launch(void* const* d_in, const int* in_sizes, int n_in,
                              void* d_out, int out_size, void* d_ws, size_t ws_size,
                              hipStream_t stream) {
    const float* x_cnn = (const float*)d_in[0];
    const float* x_eff = (const float*)d_in[1];
    const float* W_cnn = (const float*)d_in[2];
    const float* b_cnn = (const float*)d_in[3];
    const float* W_eff = (const float*)d_in[4];
    const float* b_eff = (const float*)d_in[5];
    const float* W_q   = (const float*)d_in[6];
    const float* b_q   = (const float*)d_in[7];
    const float* W_k   = (const float*)d_in[8];
    const float* b_k   = (const float*)d_in[9];
    const float* W_v   = (const float*)d_in[10];
    const float* b_v   = (const float*)d_in[11];
    const float* gamma = (const float*)d_in[12];
    float* out = (float*)d_out;

    uint8_t* ws = (uint8_t*)d_ws;
    size_t off = 0;
    auto alloc = [&](size_t bytes) -> uint8_t* {
        uint8_t* p = ws + off;
        off = (off + bytes + 255) & ~(size_t)255;
        return p;
    };

    bf16* Wall  = (bf16*)alloc((size_t)4 * WSZ * 2);            // [Wc, Wq, Wk, Wv]
    bf16* Wc_h  = Wall;
    bf16* Wq_h  = Wall + WSZ;
    bf16* Wkv_h = Wall + 2 * (size_t)WSZ;                        // [Wk;Wv] 1024x512
    bf16* Wct   = (bf16*)alloc((size_t)NHID * NHID * 2);         // Wc^T
    bf16* Wet   = (bf16*)alloc((size_t)CEFF * NHID * 2);         // We^T [1280][512]
    bf16* Wstack= (bf16*)alloc((size_t)1024 * NHID * 2);         // [Wqc ; Wc]
    bf16* Wkve  = (bf16*)alloc((size_t)1024 * CEFF * 2);         // [Wk;Wv]*We  [1024][1280]
    float* bstack = (float*)alloc(1024 * 4);                     // [bqc ; b_cnn]
    float* bkv  = (float*)alloc(1024 * 4);
    float* rowSum = (float*)alloc((size_t)NB * NTOK * 4);
    bf16* Xc_t  = (bf16*)alloc((size_t)NB * NTOK * NHID * 2);    // [b][n][c] bf16
    bf16* Xe_t  = (bf16*)alloc((size_t)NB * NTOK * CEFF * 2);    // [b][n][c] bf16; reused as P
    bf16* resid = (bf16*)alloc((size_t)NB * NHID * NTOK * 2);    // cnn_proj bf16 [c][n]
    bf16* q_t   = (bf16*)alloc((size_t)NB * NTOK * NHID * 2);
    bf16* k_t   = (bf16*)alloc((size_t)NB * NTOK * NHID * 2);
    bf16* v_nt  = (bf16*)alloc((size_t)NB * NHID * NTOK * 2);
    bf16* P     = Xe_t;   // 64MB <= 80MB; Xe_t dead after kv-gemm (stream-ordered)

    // 1) weights -> bf16 ; transposed copies for the fusion gemms
    {
        W4 w; w.s[0] = W_cnn; w.s[1] = W_q; w.s[2] = W_k; w.s[3] = W_v;
        convert_w4_kernel<<<4 * WSZ / 256, 256, 0, stream>>>(w, Wall);
    }
    transpose_to_bf16_kernel<<<dim3(NHID / 32, NHID / 32, 1), dim3(32, 8), 0, stream>>>(W_cnn, Wct, NHID, NHID);
    transpose_to_bf16_kernel<<<dim3(CEFF / 32, NHID / 32, 1), dim3(32, 8), 0, stream>>>(W_eff, Wet, NHID, CEFF);

    // 2) inputs -> bf16 [b][n][c]
    transpose_to_bf16_kernel<<<dim3(NTOK / 32, NHID / 32, NB), dim3(32, 8), 0, stream>>>(x_cnn, Xc_t, NHID, NTOK);
    transpose_to_bf16_kernel<<<dim3(NTOK / 32, CEFF / 32, NB), dim3(32, 8), 0, stream>>>(x_eff, Xe_t, CEFF, NTOK);

    // 3) fused biases (bqc -> bstack[0:512]); stack Wc / b_cnn below them
    bias_fuse_kernel<<<1536, 256, 0, stream>>>(W_q, W_k, W_v, b_cnn, b_eff, b_q, b_k, b_v, bstack, bkv);
    hipMemcpyAsync(Wstack + (size_t)NHID * NHID, Wc_h, (size_t)NHID * NHID * 2,
                   hipMemcpyDeviceToDevice, stream);
    hipMemcpyAsync(bstack + NHID, b_cnn, NHID * 4, hipMemcpyDeviceToDevice, stream);

    hipMemsetAsync(rowSum, 0, (size_t)NB * NTOK * 4, stream);

    auto gemm = [&](dim3 grid, int swiz,
                    const bf16* A, long long aS, int lda,
                    const bf16* Bt, long long bS, int ldb, int K,
                    const float* bias,
                    float* oF, long long fS, int ldf, const bf16* rH, const float* gp,
                    const float* rIn, float* rOut,
                    bf16* oHt, long long htS, int ldht, int htMax,
                    bf16* oHn, long long hnS, int ldhn, int hnBase, int doExp) {
        gemm_bt_kernel<<<grid, 256, 0, stream>>>(A, aS, lda, Bt, bS, ldb, K, swiz, bias,
                                                 oF, fS, ldf, rH, gp, rIn, rOut,
                                                 oHt, htS, ldht, htMax, oHn, hnS, ldhn, hnBase, doExp);
    };

    const long long sNC = (long long)NTOK * NHID;
    const long long sCN = (long long)NHID * NTOK;
    const long long sNE = (long long)NTOK * CEFF;
    const long long sPP = (long long)NTOK * NTOK;

    // 4) fused weights: Wqc[i][l] = sum_j Wq[i][j] Wc[j][l] -> Wstack rows 0..511
    gemm(dim3(4, 4, 1), 0, Wq_h, 0, NHID, Wct, 0, NHID, NHID, nullptr,
         nullptr, 0, 0, nullptr, nullptr, nullptr, nullptr,
         nullptr, 0, 0, 0, Wstack, 0, NHID, 0, 0);
    //    Wkve[i][e] = sum_j [Wk;Wv][i][j] We[j][e]            (1024x1280, K=512)
    gemm(dim3(10, 8, 1), 0, Wkv_h, 0, NHID, Wet, 0, NHID, NHID, nullptr,
         nullptr, 0, 0, nullptr, nullptr, nullptr, nullptr,
         nullptr, 0, 0, 0, Wkve, 0, CEFF, 0, 0);

    // 5) [q ; resid] = Wstack @ Xc : rows<512 -> q_t [n][c] (+bqc);
    //    rows>=512 -> resid [c][n] (+b_cnn)
    gemm(dim3(8, 64, 4), 1, Wstack, 0, NHID, Xc_t, sNC, NHID, NHID, bstack,
         nullptr, 0, 0, nullptr, nullptr, nullptr, nullptr,
         q_t, sNC, NHID, NHID,
         resid, sCN, NTOK, NHID, 0);
    // 6) [k;v] = Wkve @ Xe + bkv : rows<512 -> k_t [n][c]; rows>=512 -> v_nt [c][n]
    gemm(dim3(8, 64, 4), 1, Wkve, 0, CEFF, Xe_t, sNE, CEFF, CEFF, bkv,
         nullptr, 0, 0, nullptr, nullptr, nullptr, nullptr,
         k_t, sNC, NHID, NHID,
         v_nt, sCN, NTOK, NHID, 0);
    // 7) P[q][k] = exp(q.k) bf16 + atomic row sums    (writes over Xe_t)
    gemm(dim3(8, 64, 4), 1, q_t, sNC, NHID, k_t, sNC, NHID, NHID, nullptr,
         nullptr, 0, 0, nullptr, nullptr, nullptr, rowSum,
         nullptr, 0, 0, 0, P, sPP, NTOK, 0, 1);
    // 8) out[c][n] = gamma * (sum_m v[c][m] P[n][m]) / rowSum[n] + resid[c][n]
    gemm(dim3(8, 32, 4), 1, v_nt, sCN, NTOK, P, sPP, NTOK, NTOK, nullptr,
         out, sCN, NTOK, resid, gamma, rowSum, nullptr,
         nullptr, 0, 0, 0, nullptr, 0, 0, 0, 0);
}